// Round 9
// baseline (177.584 us; speedup 1.0000x reference)
//
#include <hip/hip_runtime.h>
#include <math.h>

// Round 9: single fused kernel.
//  - 1024 blocks x 256 thr, exactly 4 blocks/CU co-resident (LDS 38.1KB, VGPR<=128).
//  - Block = 64 pixels (2 rows x 32 cols) of one batch: x loaded ONCE (coalesced
//    + LDS transpose), theta/phi/origin MFMA convs, 2x2 pool completes in-block
//    -> one 16-kv K/V tile emitted as frag planes. Q never leaves LDS.
//  - Per-batch device barrier (64 arrivals, device-scope atomics + threadfence,
//    bounded spin tripwire), then R8's register-chained split-KV attention,
//    bf16 LDS merge, MFMA W-conv epilogue with residual from resident LDS x.

#define B_SZ 16
#define HW 4096
#define MST 40     // merge/y row stride (ushorts)
#define LOG2E 1.4426950408889634f

typedef __attribute__((ext_vector_type(8))) short bfrag;
typedef __attribute__((ext_vector_type(4))) short sfrag;
typedef __attribute__((ext_vector_type(4))) float f32x4;

static __device__ __forceinline__ ushort f2bf(float v) {
  union { float f; uint u; } c; c.f = v;
  uint b = c.u + 0x7FFFu + ((c.u >> 16) & 1u);
  return (ushort)(b >> 16);
}
static __device__ __forceinline__ float bf2f(ushort h) {
  union { uint u; float f; } c; c.u = (uint)h << 16; return c.f;
}

__global__ __launch_bounds__(256, 4) void k_fused(
    const float* __restrict__ x,
    const float* __restrict__ wt, const float* __restrict__ bt,
    const float* __restrict__ wp, const float* __restrict__ bp,
    const float* __restrict__ wo, const float* __restrict__ bo,
    const float* __restrict__ wW, const float* __restrict__ bW,
    ushort* __restrict__ KH, ushort* __restrict__ KL, ushort* __restrict__ VF,
    uint* __restrict__ ctr, float* __restrict__ z) {
  // LDS: sx [64][65] f32 (16640 B, lives whole kernel) | region2 (21504 B):
  //   phase A: sQ [64][33] f32 (8448) + sPool [2][32][33] f32 (8448)
  //   phase B: mrg [4][64][40] bf16 (20480) + sS [4][64] f32 (1024)
  //   phase C: yH/yL [64][40] bf16 x2 (10240)
  __shared__ __align__(16) char smem_raw[16640 + 21504];
  float*  sx    = (float*)smem_raw;
  char*   reg2  = smem_raw + 16640;
  float*  sQ    = (float*)reg2;
  float*  sPool = (float*)(reg2 + 8448);
  ushort* mrg   = (ushort*)reg2;
  float*  sS    = (float*)(reg2 + 20480);
  ushort* yH    = (ushort*)reg2;
  ushort* yL    = yH + 64 * MST;

  int t = threadIdx.x;
  int w = t >> 6, lane = t & 63, l15 = lane & 15, quad = lane >> 4;
  int b = blockIdx.x;
  int bb = b >> 6, s = b & 63, r = s >> 1, j = s & 1;
  const float* xb = x + ((size_t)bb << 18);
  int grow0 = 2 * r, gcol0 = 32 * j;

  // ---------- phase 1: coalesced x load + transpose to sx[pix][ch] ----------
  #pragma unroll
  for (int i = 0; i < 4; ++i) {
    int f = i * 256 + t;                    // 1024 float4s = 64ch x 64pix
    int ch = f >> 4, rem = f & 15, lrow = rem >> 3, c4 = rem & 7;
    float4 v = *(const float4*)(xb + (size_t)ch * 4096
                                   + (size_t)(grow0 + lrow) * 64 + gcol0 + c4 * 4);
    int lp = lrow * 32 + c4 * 4;
    sx[(lp+0)*65 + ch] = v.x; sx[(lp+1)*65 + ch] = v.y;
    sx[(lp+2)*65 + ch] = v.z; sx[(lp+3)*65 + ch] = v.w;
  }
  __syncthreads();

  // ---------- phase 2: x A-frags (hi/lo, 2 k-halves) ----------
  int lpix = w * 16 + l15;
  bfrag xh[2], xl[2];
  #pragma unroll
  for (int kh2 = 0; kh2 < 2; ++kh2)
    #pragma unroll
    for (int jj = 0; jj < 8; ++jj) {
      float v = sx[lpix * 65 + kh2 * 32 + quad * 8 + jj];
      ushort hb = f2bf(v);
      xh[kh2][jj] = (short)hb;
      xl[kh2][jj] = (short)f2bf(v - bf2f(hb));
    }

  f32x4 acc[2];

  // ---------- phase 3a: THETA (x LOG2E), 3-term -> sQ fp32 ----------
  acc[0] = (f32x4){0.f,0.f,0.f,0.f}; acc[1] = (f32x4){0.f,0.f,0.f,0.f};
  #pragma unroll
  for (int kh2 = 0; kh2 < 2; ++kh2)
    #pragma unroll
    for (int nt = 0; nt < 2; ++nt) {
      bfrag wh, wl;
      const float* wrow = wt + (size_t)(nt * 16 + l15) * 64 + kh2 * 32 + quad * 8;
      #pragma unroll
      for (int jj = 0; jj < 8; ++jj) {
        float v = wrow[jj] * LOG2E;
        ushort hb = f2bf(v);
        wh[jj] = (short)hb; wl[jj] = (short)f2bf(v - bf2f(hb));
      }
      acc[nt] = __builtin_amdgcn_mfma_f32_16x16x32_bf16(xh[kh2], wh, acc[nt], 0, 0, 0);
      acc[nt] = __builtin_amdgcn_mfma_f32_16x16x32_bf16(xl[kh2], wh, acc[nt], 0, 0, 0);
      acc[nt] = __builtin_amdgcn_mfma_f32_16x16x32_bf16(xh[kh2], wl, acc[nt], 0, 0, 0);
    }
  #pragma unroll
  for (int nt = 0; nt < 2; ++nt) {
    float bias = bt[nt * 16 + l15] * LOG2E;
    #pragma unroll
    for (int rr = 0; rr < 4; ++rr)
      sQ[(w * 16 + quad * 4 + rr) * 33 + nt * 16 + l15] = acc[nt][rr] + bias;
  }

  int hp = w * 8 + quad * 2;   // horizontal-pooled index base for this lane's rows

  // ---------- phase 3b: PHI, 3-term -> horizontal max into sPool[0] ----------
  acc[0] = (f32x4){0.f,0.f,0.f,0.f}; acc[1] = (f32x4){0.f,0.f,0.f,0.f};
  #pragma unroll
  for (int kh2 = 0; kh2 < 2; ++kh2)
    #pragma unroll
    for (int nt = 0; nt < 2; ++nt) {
      bfrag wh, wl;
      const float* wrow = wp + (size_t)(nt * 16 + l15) * 64 + kh2 * 32 + quad * 8;
      #pragma unroll
      for (int jj = 0; jj < 8; ++jj) {
        float v = wrow[jj];
        ushort hb = f2bf(v);
        wh[jj] = (short)hb; wl[jj] = (short)f2bf(v - bf2f(hb));
      }
      acc[nt] = __builtin_amdgcn_mfma_f32_16x16x32_bf16(xh[kh2], wh, acc[nt], 0, 0, 0);
      acc[nt] = __builtin_amdgcn_mfma_f32_16x16x32_bf16(xl[kh2], wh, acc[nt], 0, 0, 0);
      acc[nt] = __builtin_amdgcn_mfma_f32_16x16x32_bf16(xh[kh2], wl, acc[nt], 0, 0, 0);
    }
  #pragma unroll
  for (int nt = 0; nt < 2; ++nt) {
    float bias = bp[nt * 16 + l15];
    sPool[(0 * 32 + hp    ) * 33 + nt * 16 + l15] = fmaxf(acc[nt][0], acc[nt][1]) + bias;
    sPool[(0 * 32 + hp + 1) * 33 + nt * 16 + l15] = fmaxf(acc[nt][2], acc[nt][3]) + bias;
  }

  // ---------- phase 3c: ORIGIN (V), 2-term -> sPool[1] ----------
  acc[0] = (f32x4){0.f,0.f,0.f,0.f}; acc[1] = (f32x4){0.f,0.f,0.f,0.f};
  #pragma unroll
  for (int kh2 = 0; kh2 < 2; ++kh2)
    #pragma unroll
    for (int nt = 0; nt < 2; ++nt) {
      bfrag wh;
      const float* wrow = wo + (size_t)(nt * 16 + l15) * 64 + kh2 * 32 + quad * 8;
      #pragma unroll
      for (int jj = 0; jj < 8; ++jj) wh[jj] = (short)f2bf(wrow[jj]);
      acc[nt] = __builtin_amdgcn_mfma_f32_16x16x32_bf16(xh[kh2], wh, acc[nt], 0, 0, 0);
      acc[nt] = __builtin_amdgcn_mfma_f32_16x16x32_bf16(xl[kh2], wh, acc[nt], 0, 0, 0);
    }
  #pragma unroll
  for (int nt = 0; nt < 2; ++nt) {
    float bias = bo[nt * 16 + l15];
    sPool[(1 * 32 + hp    ) * 33 + nt * 16 + l15] = fmaxf(acc[nt][0], acc[nt][1]) + bias;
    sPool[(1 * 32 + hp + 1) * 33 + nt * 16 + l15] = fmaxf(acc[nt][2], acc[nt][3]) + bias;
  }
  __syncthreads();

  // ---------- phase 4: vertical max + emit K/V frag planes ----------
  int tile = bb * 64 + s;
  #pragma unroll
  for (int f = t; f < 512; f += 256) {   // K: 64 lanes x 8 regs
    int ln = f >> 3, ji = f & 7;
    int kv = ln & 15, ch = (ln >> 4) * 8 + ji;
    float v = fmaxf(sPool[(0 * 32 + kv) * 33 + ch], sPool[(0 * 32 + 16 + kv) * 33 + ch]);
    ushort hb = f2bf(v);
    size_t base = ((size_t)tile * 64 + ln) * 8 + ji;
    KH[base] = hb;
    KL[base] = f2bf(v - bf2f(hb));
  }
  #pragma unroll
  for (int f = t; f < 512; f += 256) {   // V: 2 mt x 64 lanes x 4 regs
    int mt = f >> 8, ln = (f >> 2) & 63, jv = f & 3;
    int kv = ((ln >> 4) << 2) + jv, ch = mt * 16 + (ln & 15);
    float v = fmaxf(sPool[(1 * 32 + kv) * 33 + ch], sPool[(1 * 32 + 16 + kv) * 33 + ch]);
    VF[(((size_t)tile * 2 + mt) * 64 + ln) * 4 + jv] = f2bf(v);
  }

  // ---------- phase 5: per-batch device barrier (64 arrivals) ----------
  __syncthreads();
  if (t == 0) {
    uint* cb = ctr + bb * 16;            // 64B-spaced counters
    __threadfence();                     // release: push K/V to device scope
    atomicAdd(cb, 1u);
    int it = 0;
    while (atomicAdd(cb, 0u) < 64u && ++it < (1 << 26))
      __builtin_amdgcn_s_sleep(4);
    __threadfence();                     // acquire: invalidate stale lines
  }
  __syncthreads();

  // ---------- phase 6: Q frags, then register-chained split-KV attention ----------
  bfrag qh[4], ql[4];
  #pragma unroll
  for (int qt = 0; qt < 4; ++qt)
    #pragma unroll
    for (int jj = 0; jj < 8; ++jj) {
      float v = sQ[(qt * 16 + l15) * 33 + quad * 8 + jj];
      ushort hb = f2bf(v);
      qh[qt][jj] = (short)hb;
      ql[qt][jj] = (short)f2bf(v - bf2f(hb));
    }
  __syncthreads();                       // sQ/sPool dead -> region2 reusable

  const ushort* KHb = KH + (size_t)bb * 64 * 64 * 8;
  const ushort* KLb = KL + (size_t)bb * 64 * 64 * 8;
  const ushort* VFb = VF + (size_t)bb * 64 * 2 * 64 * 4;

  f32x4 accO[4][2];
  float spart[4] = {0.f, 0.f, 0.f, 0.f};
  #pragma unroll
  for (int qt = 0; qt < 4; ++qt) {
    accO[qt][0] = (f32x4){0.f,0.f,0.f,0.f};
    accO[qt][1] = (f32x4){0.f,0.f,0.f,0.f};
  }

  bfrag kh[2], kl[2];
  sfrag vf[2][2];
  auto loadT = [&](int buf, int i) {
    int gt = w * 16 + i;
    size_t kb = ((size_t)gt * 64 + lane) * 8;
    kh[buf] = *(const bfrag*)(KHb + kb);
    kl[buf] = *(const bfrag*)(KLb + kb);
    vf[buf][0] = *(const sfrag*)(VFb + (((size_t)gt * 2 + 0) * 64 + lane) * 4);
    vf[buf][1] = *(const sfrag*)(VFb + (((size_t)gt * 2 + 1) * 64 + lane) * 4);
  };

  loadT(0, 0);
  #pragma unroll 2
  for (int i = 0; i < 16; ++i) {
    int cur = i & 1;
    if (i < 15) loadT(cur ^ 1, i + 1);
    #pragma unroll
    for (int qt = 0; qt < 4; ++qt) {
      f32x4 sv = (f32x4){0.f,0.f,0.f,0.f};
      sv = __builtin_amdgcn_mfma_f32_16x16x32_bf16(kh[cur], qh[qt], sv, 0, 0, 0);
      sv = __builtin_amdgcn_mfma_f32_16x16x32_bf16(kh[cur], ql[qt], sv, 0, 0, 0);
      sv = __builtin_amdgcn_mfma_f32_16x16x32_bf16(kl[cur], qh[qt], sv, 0, 0, 0);
      float e0 = exp2f(sv[0]), e1 = exp2f(sv[1]);
      float e2 = exp2f(sv[2]), e3 = exp2f(sv[3]);
      spart[qt] += (e0 + e1) + (e2 + e3);
      union { uint2 u; sfrag s4; } pk;
      pk.u.x = (__float_as_uint(e0) >> 16) | (__float_as_uint(e1) & 0xFFFF0000u);
      pk.u.y = (__float_as_uint(e2) >> 16) | (__float_as_uint(e3) & 0xFFFF0000u);
      accO[qt][0] = __builtin_amdgcn_mfma_f32_16x16x16bf16_1k(vf[cur][0], pk.s4, accO[qt][0], 0, 0, 0);
      accO[qt][1] = __builtin_amdgcn_mfma_f32_16x16x16bf16_1k(vf[cur][1], pk.s4, accO[qt][1], 0, 0, 0);
    }
  }

  // ---------- phase 7: merge partials (bf16) + normalize ----------
  #pragma unroll
  for (int qt = 0; qt < 4; ++qt) {
    spart[qt] += __shfl_xor(spart[qt], 16);
    spart[qt] += __shfl_xor(spart[qt], 32);
  }
  #pragma unroll
  for (int qt = 0; qt < 4; ++qt) {
    #pragma unroll
    for (int mt = 0; mt < 2; ++mt)
      #pragma unroll
      for (int rr = 0; rr < 4; ++rr)
        mrg[(w * 64 + qt * 16 + l15) * MST + mt * 16 + quad * 4 + rr] =
            f2bf(accO[qt][mt][rr]);
    if (lane < 16) sS[w * 64 + qt * 16 + l15] = spart[qt];
  }
  __syncthreads();

  int rq = t >> 2, rc = (t & 3) * 8;
  float yv[8];
  {
    float ssum = sS[rq] + sS[64 + rq] + sS[128 + rq] + sS[192 + rq];
    float inv = 1.0f / ssum;
    #pragma unroll
    for (int jj = 0; jj < 8; ++jj) {
      float acc8 = bf2f(mrg[(size_t)rq * MST + rc + jj])
                 + bf2f(mrg[(size_t)(64 + rq) * MST + rc + jj])
                 + bf2f(mrg[(size_t)(128 + rq) * MST + rc + jj])
                 + bf2f(mrg[(size_t)(192 + rq) * MST + rc + jj]);
      yv[jj] = acc8 * inv;
    }
  }
  __syncthreads();

  // ---------- phase 8: y bf16 hi/lo planes + MFMA W-conv + residual ----------
  {
    union { ushort u[8]; uint4 v4; } Hh, Ll;
    #pragma unroll
    for (int jj = 0; jj < 8; ++jj) {
      ushort hb = f2bf(yv[jj]);
      Hh.u[jj] = hb;
      Ll.u[jj] = f2bf(yv[jj] - bf2f(hb));
    }
    *(uint4*)&yH[rq * MST + rc] = Hh.v4;
    *(uint4*)&yL[rq * MST + rc] = Ll.v4;
  }
  __syncthreads();

  #pragma unroll
  for (int nt = 0; nt < 4; ++nt) {
    f32x4 d = (f32x4){0.f,0.f,0.f,0.f};
    #pragma unroll
    for (int kt = 0; kt < 2; ++kt) {
      float4 w4 = *(const float4*)&wW[(size_t)(w * 16 + l15) * 32 + kt * 16 + quad * 4];
      sfrag ah, al, yhf, ylf;
      #pragma unroll
      for (int jj = 0; jj < 4; ++jj) {
        float v = (&w4.x)[jj];
        ushort hb = f2bf(v);
        ah[jj] = (short)hb; al[jj] = (short)f2bf(v - bf2f(hb));
      }
      yhf = *(const sfrag*)&yH[(nt * 16 + l15) * MST + kt * 16 + quad * 4];
      ylf = *(const sfrag*)&yL[(nt * 16 + l15) * MST + kt * 16 + quad * 4];
      d = __builtin_amdgcn_mfma_f32_16x16x16bf16_1k(ah, yhf, d, 0, 0, 0);
      d = __builtin_amdgcn_mfma_f32_16x16x16bf16_1k(al, yhf, d, 0, 0, 0);
      d = __builtin_amdgcn_mfma_f32_16x16x16bf16_1k(ah, ylf, d, 0, 0, 0);
    }
    #pragma unroll
    for (int rr = 0; rr < 4; ++rr) {
      int cout = w * 16 + quad * 4 + rr;
      int lp = nt * 16 + l15;
      float xres = sx[lp * 65 + cout];
      size_t zi = ((size_t)bb << 18) + ((size_t)cout << 12)
                + (size_t)(grow0 + (lp >> 5)) * 64 + gcol0 + (lp & 31);
      z[zi] = d[rr] + bW[cout] + xres;
    }
  }
}

extern "C" void kernel_launch(void* const* d_in, const int* in_sizes, int n_in,
                              void* d_out, int out_size, void* d_ws, size_t ws_size,
                              hipStream_t stream) {
  const float* x   = (const float*)d_in[0];
  const float* w_o = (const float*)d_in[1];
  const float* b_o = (const float*)d_in[2];
  const float* w_t = (const float*)d_in[3];
  const float* b_t = (const float*)d_in[4];
  const float* w_p = (const float*)d_in[5];
  const float* b_p = (const float*)d_in[6];
  const float* w_W = (const float*)d_in[7];
  const float* b_W = (const float*)d_in[8];
  float* z = (float*)d_out;

  uint*   ctr = (uint*)d_ws;                          // 16 counters, 64B apart
  ushort* KH  = (ushort*)((char*)d_ws + 1024);        // 1024 tiles * 64 * 8
  ushort* KL  = KH + 524288;
  ushort* VF  = KL + 524288;                          // 1024 tiles * 2*64*4

  hipMemsetAsync(d_ws, 0, 1024, stream);              // zero barrier counters
  k_fused<<<dim3(1024), dim3(256), 0, stream>>>(
      x, w_t, b_t, w_p, b_p, w_o, b_o, w_W, b_W, KH, KL, VF, ctr, z);
}

// Round 10
// 137.538 us; speedup vs baseline: 1.2912x; 1.2912x over previous
//
#include <hip/hip_runtime.h>
#include <math.h>

// Round 10 = Round 8 + targeted k_attn fixes:
//  - S = K_exact . Q_bf16 (2 serial MFMAs, was 3; QL plane removed).
//  - bf16 partial-O merge (LDS 37.9 -> 21.5 KB; kills the 3-blocks/CU cliff
//    seen in R9's occupancy counter).
//  - K/V prefetch distance 2 tiles (pair ping-pong buffers).
// k_qkv unchanged from R8 except QL emit removed.

#define B_SZ 16
#define HW 4096
#define XSTR 65
#define MST 40     // merge/y row stride (ushorts)
#define LOG2E 1.4426950408889634f

typedef __attribute__((ext_vector_type(8))) short bfrag;
typedef __attribute__((ext_vector_type(4))) short sfrag;
typedef __attribute__((ext_vector_type(4))) float f32x4;

static __device__ __forceinline__ ushort f2bf(float v) {
  union { float f; uint u; } c; c.f = v;
  uint b = c.u + 0x7FFFu + ((c.u >> 16) & 1u);
  return (ushort)(b >> 16);
}
static __device__ __forceinline__ float bf2f(ushort h) {
  union { uint u; float f; } c; c.u = (uint)h << 16; return c.f;
}

// ---------------- kernel 1: Q/K/V via MFMA -> swizzled frag planes ----------------
// 512 thr = 8 waves; block = 128 pixels = 2 image rows; grid = 16*32.
__global__ __launch_bounds__(512) void k_qkv(
    const float* __restrict__ x,
    const float* __restrict__ wt, const float* __restrict__ bt,
    const float* __restrict__ wp, const float* __restrict__ bp,
    const float* __restrict__ wo, const float* __restrict__ bo,
    ushort* __restrict__ QH,
    ushort* __restrict__ KH, ushort* __restrict__ KL, ushort* __restrict__ VF) {
  __shared__ float sx[128 * XSTR];              // [pix][ch] (reused for theta)
  __shared__ float sPool[2][2][32][33];

  int t = threadIdx.x;
  int W = t >> 6, lane = t & 63, l15 = lane & 15, quad = lane >> 4;
  int bb = blockIdx.x >> 5, rg = blockIdx.x & 31;
  int p0 = rg * 128;

  // coalesced x load + transpose to [pix][ch]
  #pragma unroll
  for (int i = 0; i < 4; ++i) {
    int f = i * 512 + t;
    int c = f >> 5, u = f & 31;
    float4 v = *(const float4*)(x + ((size_t)bb << 18) + (size_t)c * HW + p0 + 4 * u);
    sx[(4*u+0) * XSTR + c] = v.x;
    sx[(4*u+1) * XSTR + c] = v.y;
    sx[(4*u+2) * XSTR + c] = v.z;
    sx[(4*u+3) * XSTR + c] = v.w;
  }
  __syncthreads();

  // x A-frags (hi/lo, 2 k-halves) from LDS
  int pix = W * 16 + l15;
  bfrag xh[2], xl[2];
  #pragma unroll
  for (int kh2 = 0; kh2 < 2; ++kh2)
    #pragma unroll
    for (int j = 0; j < 8; ++j) {
      float v = sx[pix * XSTR + kh2 * 32 + quad * 8 + j];
      ushort hb = f2bf(v);
      xh[kh2][j] = (short)hb;
      xl[kh2][j] = (short)f2bf(v - bf2f(hb));
    }
  __syncthreads();

  f32x4 acc[2];

  // THETA (x LOG2E), 3-term -> fp32 back into sx
  acc[0] = (f32x4){0.f,0.f,0.f,0.f}; acc[1] = (f32x4){0.f,0.f,0.f,0.f};
  #pragma unroll
  for (int kh2 = 0; kh2 < 2; ++kh2)
    #pragma unroll
    for (int nt = 0; nt < 2; ++nt) {
      bfrag wh, wl;
      const float* wrow = wt + (size_t)(nt * 16 + l15) * 64 + kh2 * 32 + quad * 8;
      #pragma unroll
      for (int j = 0; j < 8; ++j) {
        float v = wrow[j] * LOG2E;
        ushort hb = f2bf(v);
        wh[j] = (short)hb; wl[j] = (short)f2bf(v - bf2f(hb));
      }
      acc[nt] = __builtin_amdgcn_mfma_f32_16x16x32_bf16(xh[kh2], wh, acc[nt], 0, 0, 0);
      acc[nt] = __builtin_amdgcn_mfma_f32_16x16x32_bf16(xl[kh2], wh, acc[nt], 0, 0, 0);
      acc[nt] = __builtin_amdgcn_mfma_f32_16x16x32_bf16(xh[kh2], wl, acc[nt], 0, 0, 0);
    }
  #pragma unroll
  for (int nt = 0; nt < 2; ++nt) {
    float bias = bt[nt * 16 + l15] * LOG2E;
    #pragma unroll
    for (int r = 0; r < 4; ++r)
      sx[(W * 16 + quad * 4 + r) * XSTR + nt * 16 + l15] = acc[nt][r] + bias;
  }

  int prow = (W * 16 + quad * 4) >> 6;
  int px2  = ((W * 16 + quad * 4) & 63) >> 1;

  // PHI, 3-term -> horizontal-pair max into sPool[0]
  acc[0] = (f32x4){0.f,0.f,0.f,0.f}; acc[1] = (f32x4){0.f,0.f,0.f,0.f};
  #pragma unroll
  for (int kh2 = 0; kh2 < 2; ++kh2)
    #pragma unroll
    for (int nt = 0; nt < 2; ++nt) {
      bfrag wh, wl;
      const float* wrow = wp + (size_t)(nt * 16 + l15) * 64 + kh2 * 32 + quad * 8;
      #pragma unroll
      for (int j = 0; j < 8; ++j) {
        float v = wrow[j];
        ushort hb = f2bf(v);
        wh[j] = (short)hb; wl[j] = (short)f2bf(v - bf2f(hb));
      }
      acc[nt] = __builtin_amdgcn_mfma_f32_16x16x32_bf16(xh[kh2], wh, acc[nt], 0, 0, 0);
      acc[nt] = __builtin_amdgcn_mfma_f32_16x16x32_bf16(xl[kh2], wh, acc[nt], 0, 0, 0);
      acc[nt] = __builtin_amdgcn_mfma_f32_16x16x32_bf16(xh[kh2], wl, acc[nt], 0, 0, 0);
    }
  #pragma unroll
  for (int nt = 0; nt < 2; ++nt) {
    float bias = bp[nt * 16 + l15];
    sPool[0][prow][px2    ][nt * 16 + l15] = fmaxf(acc[nt][0], acc[nt][1]) + bias;
    sPool[0][prow][px2 + 1][nt * 16 + l15] = fmaxf(acc[nt][2], acc[nt][3]) + bias;
  }

  // ORIGIN (V), 2-term -> sPool[1]
  acc[0] = (f32x4){0.f,0.f,0.f,0.f}; acc[1] = (f32x4){0.f,0.f,0.f,0.f};
  #pragma unroll
  for (int kh2 = 0; kh2 < 2; ++kh2)
    #pragma unroll
    for (int nt = 0; nt < 2; ++nt) {
      bfrag wh;
      const float* wrow = wo + (size_t)(nt * 16 + l15) * 64 + kh2 * 32 + quad * 8;
      #pragma unroll
      for (int j = 0; j < 8; ++j) wh[j] = (short)f2bf(wrow[j]);
      acc[nt] = __builtin_amdgcn_mfma_f32_16x16x32_bf16(xh[kh2], wh, acc[nt], 0, 0, 0);
      acc[nt] = __builtin_amdgcn_mfma_f32_16x16x32_bf16(xl[kh2], wh, acc[nt], 0, 0, 0);
    }
  #pragma unroll
  for (int nt = 0; nt < 2; ++nt) {
    float bias = bo[nt * 16 + l15];
    sPool[1][prow][px2    ][nt * 16 + l15] = fmaxf(acc[nt][0], acc[nt][1]) + bias;
    sPool[1][prow][px2 + 1][nt * 16 + l15] = fmaxf(acc[nt][2], acc[nt][3]) + bias;
  }
  __syncthreads();

  // emit Q frags (hi only): QH[((bb*256+gqt)*64+lane)*8+j] = theta[q][ch]
  {
    int qt = t >> 6, ln = t & 63, fl = ln & 15, fq = ln >> 4;
    union { ushort u[8]; uint4 v; } Hh;
    #pragma unroll
    for (int j = 0; j < 8; ++j)
      Hh.u[j] = f2bf(sx[(qt * 16 + fl) * XSTR + fq * 8 + j]);
    *(uint4*)(QH + ((size_t)(bb * 256 + rg * 8 + qt) * 64 + ln) * 8) = Hh.v;
  }

  // emit K frags (hi/lo)
  #pragma unroll
  for (int f = t; f < 1024; f += 512) {
    int tt = f >> 9, rem = f & 511;
    int ln = rem >> 3, j = rem & 7;
    int kvl = tt * 16 + (ln & 15);
    int ch = (ln >> 4) * 8 + j;
    float v = fmaxf(sPool[0][0][kvl][ch], sPool[0][1][kvl][ch]);
    ushort hb = f2bf(v);
    size_t base = ((size_t)(bb * 64 + rg * 2 + tt) * 64 + ln) * 8 + j;
    KH[base] = hb;
    KL[base] = f2bf(v - bf2f(hb));
  }

  // emit V frags
  #pragma unroll
  for (int f = t; f < 1024; f += 512) {
    int tt = f >> 9, mt = (f >> 8) & 1;
    int ln = (f >> 2) & 63, j = f & 3;
    int kvl = tt * 16 + ((ln >> 4) << 2) + j;
    int ch = mt * 16 + (ln & 15);
    float v = fmaxf(sPool[1][0][kvl][ch], sPool[1][1][kvl][ch]);
    VF[(((size_t)(bb * 64 + rg * 2 + tt) * 2 + mt) * 64 + ln) * 4 + j] = f2bf(v);
  }
}

// ---------------- kernel 2: register-chained flash attention ----------------
// 256 thr = 4 waves; block = 64 q (4 tiles); wave w owns kv [w*256, w*256+256).
__global__ __launch_bounds__(256, 4) void k_attn(
    const ushort* __restrict__ QH,
    const ushort* __restrict__ KH, const ushort* __restrict__ KL,
    const ushort* __restrict__ VF,
    const float* __restrict__ x, const float* __restrict__ wW,
    const float* __restrict__ bW, float* __restrict__ z) {
  // 21504 B: mrg bf16 [4][64][MST] (20480) + sS f32 [4][64] (1024); yH/yL reuse mrg.
  __shared__ __align__(16) char smem_raw[20480 + 1024];
  ushort* mrg = (ushort*)smem_raw;
  float*  sS  = (float*)(smem_raw + 20480);
  ushort* yH  = (ushort*)smem_raw;
  ushort* yL  = yH + 64 * MST;

  int t = threadIdx.x;
  int w = t >> 6, lane = t & 63, l15 = lane & 15, quad = lane >> 4;
  int bb = blockIdx.x >> 6;
  int bq = blockIdx.x & 63;

  // Q frags (B[k=ch][n=q]), bf16 only
  bfrag qh[4];
  #pragma unroll
  for (int qt = 0; qt < 4; ++qt)
    qh[qt] = *(const bfrag*)(QH + ((size_t)(bb * 256 + bq * 4 + qt) * 64 + lane) * 8);

  const ushort* KHb = KH + (size_t)bb * 64 * 64 * 8;
  const ushort* KLb = KL + (size_t)bb * 64 * 64 * 8;
  const ushort* VFb = VF + (size_t)bb * 64 * 2 * 64 * 4;

  f32x4 accO[4][2];
  float spart[4] = {0.f, 0.f, 0.f, 0.f};
  #pragma unroll
  for (int qt = 0; qt < 4; ++qt) {
    accO[qt][0] = (f32x4){0.f,0.f,0.f,0.f};
    accO[qt][1] = (f32x4){0.f,0.f,0.f,0.f};
  }

  bfrag kh[2][2], kl[2][2];
  sfrag vf[2][2][2];
  auto loadPair = [&](int buf, int p) {     // tiles 2p, 2p+1 of this wave's 16
    #pragma unroll
    for (int u = 0; u < 2; ++u) {
      int gt = w * 16 + p * 2 + u;
      size_t kb = ((size_t)gt * 64 + lane) * 8;
      kh[buf][u] = *(const bfrag*)(KHb + kb);
      kl[buf][u] = *(const bfrag*)(KLb + kb);
      vf[buf][u][0] = *(const sfrag*)(VFb + (((size_t)gt * 2 + 0) * 64 + lane) * 4);
      vf[buf][u][1] = *(const sfrag*)(VFb + (((size_t)gt * 2 + 1) * 64 + lane) * 4);
    }
  };

  loadPair(0, 0);
  #pragma unroll 2
  for (int p = 0; p < 8; ++p) {
    int cur = p & 1;
    if (p < 7) loadPair(cur ^ 1, p + 1);    // prefetch next pair (2 tiles ahead)
    #pragma unroll
    for (int u = 0; u < 2; ++u) {
      #pragma unroll
      for (int qt = 0; qt < 4; ++qt) {
        f32x4 sv = (f32x4){0.f,0.f,0.f,0.f};
        sv = __builtin_amdgcn_mfma_f32_16x16x32_bf16(kh[cur][u], qh[qt], sv, 0, 0, 0);
        sv = __builtin_amdgcn_mfma_f32_16x16x32_bf16(kl[cur][u], qh[qt], sv, 0, 0, 0);
        float e0 = exp2f(sv[0]), e1 = exp2f(sv[1]);
        float e2 = exp2f(sv[2]), e3 = exp2f(sv[3]);
        spart[qt] += (e0 + e1) + (e2 + e3);
        union { uint2 uu; sfrag s4; } pk;   // trunc-to-bf16: normalization cancels bias
        pk.uu.x = (__float_as_uint(e0) >> 16) | (__float_as_uint(e1) & 0xFFFF0000u);
        pk.uu.y = (__float_as_uint(e2) >> 16) | (__float_as_uint(e3) & 0xFFFF0000u);
        accO[qt][0] = __builtin_amdgcn_mfma_f32_16x16x16bf16_1k(vf[cur][u][0], pk.s4, accO[qt][0], 0, 0, 0);
        accO[qt][1] = __builtin_amdgcn_mfma_f32_16x16x16bf16_1k(vf[cur][u][1], pk.s4, accO[qt][1], 0, 0, 0);
      }
    }
  }

  // reduce spart across quads; stash partials (bf16 O, fp32 sums)
  #pragma unroll
  for (int qt = 0; qt < 4; ++qt) {
    spart[qt] += __shfl_xor(spart[qt], 16);
    spart[qt] += __shfl_xor(spart[qt], 32);
  }
  #pragma unroll
  for (int qt = 0; qt < 4; ++qt) {
    #pragma unroll
    for (int mt = 0; mt < 2; ++mt)
      #pragma unroll
      for (int rr = 0; rr < 4; ++rr)
        mrg[(w * 64 + qt * 16 + l15) * MST + mt * 16 + quad * 4 + rr] =
            f2bf(accO[qt][mt][rr]);
    if (lane < 16) sS[w * 64 + qt * 16 + l15] = spart[qt];
  }
  __syncthreads();

  // reduce over waves + normalize (thread -> q = t>>2, 8 channels)
  int rq = t >> 2, rc = (t & 3) * 8;
  float yv[8];
  {
    float ssum = sS[rq] + sS[64 + rq] + sS[128 + rq] + sS[192 + rq];
    float inv = 1.0f / ssum;
    #pragma unroll
    for (int jj = 0; jj < 8; ++jj) {
      float a8 = bf2f(mrg[(size_t)rq * MST + rc + jj])
               + bf2f(mrg[(size_t)(64 + rq) * MST + rc + jj])
               + bf2f(mrg[(size_t)(128 + rq) * MST + rc + jj])
               + bf2f(mrg[(size_t)(192 + rq) * MST + rc + jj]);
      yv[jj] = a8 * inv;
    }
  }
  __syncthreads();

  // y bf16 hi/lo planes
  {
    union { ushort u[8]; uint4 v4; } Hh, Ll;
    #pragma unroll
    for (int jj = 0; jj < 8; ++jj) {
      ushort hb = f2bf(yv[jj]);
      Hh.u[jj] = hb;
      Ll.u[jj] = f2bf(yv[jj] - bf2f(hb));
    }
    *(uint4*)&yH[rq * MST + rc] = Hh.v4;
    *(uint4*)&yL[rq * MST + rc] = Ll.v4;
  }
  __syncthreads();

  // epilogue: wave w -> cout tile [w*16, w*16+16); z = W.y + bW + x
  #pragma unroll
  for (int nt = 0; nt < 4; ++nt) {
    f32x4 d = (f32x4){0.f,0.f,0.f,0.f};
    #pragma unroll
    for (int kt = 0; kt < 2; ++kt) {
      float4 w4 = *(const float4*)&wW[(size_t)(w * 16 + l15) * 32 + kt * 16 + quad * 4];
      sfrag ah, al, yhf, ylf;
      #pragma unroll
      for (int jj = 0; jj < 4; ++jj) {
        float v = (&w4.x)[jj];
        ushort hb = f2bf(v);
        ah[jj] = (short)hb; al[jj] = (short)f2bf(v - bf2f(hb));
      }
      yhf = *(const sfrag*)&yH[(nt * 16 + l15) * MST + kt * 16 + quad * 4];
      ylf = *(const sfrag*)&yL[(nt * 16 + l15) * MST + kt * 16 + quad * 4];
      d = __builtin_amdgcn_mfma_f32_16x16x16bf16_1k(ah, yhf, d, 0, 0, 0);
      d = __builtin_amdgcn_mfma_f32_16x16x16bf16_1k(al, yhf, d, 0, 0, 0);
      d = __builtin_amdgcn_mfma_f32_16x16x16bf16_1k(ah, ylf, d, 0, 0, 0);
    }
    #pragma unroll
    for (int rr = 0; rr < 4; ++rr) {
      int cout = w * 16 + quad * 4 + rr;
      size_t zi = ((size_t)bb << 18) + ((size_t)cout << 12)
                + (size_t)(bq * 4 + nt) * 16 + l15;
      z[zi] = d[rr] + bW[cout] + x[zi];
    }
  }
}

extern "C" void kernel_launch(void* const* d_in, const int* in_sizes, int n_in,
                              void* d_out, int out_size, void* d_ws, size_t ws_size,
                              hipStream_t stream) {
  const float* x   = (const float*)d_in[0];
  const float* w_o = (const float*)d_in[1];
  const float* b_o = (const float*)d_in[2];
  const float* w_t = (const float*)d_in[3];
  const float* b_t = (const float*)d_in[4];
  const float* w_p = (const float*)d_in[5];
  const float* b_p = (const float*)d_in[6];
  const float* w_W = (const float*)d_in[7];
  const float* b_W = (const float*)d_in[8];
  float* z = (float*)d_out;

  ushort* QH = (ushort*)d_ws;                         // 16*256*64*8 = 2097152
  ushort* KH = QH + 2097152;                          // 16*64*64*8  = 524288
  ushort* KL = KH + 524288;
  ushort* VF = KL + 524288;                           // 16*64*2*64*4 = 524288

  k_qkv<<<dim3(B_SZ * 32), dim3(512), 0, stream>>>(
      x, w_t, b_t, w_p, b_p, w_o, b_o, QH, KH, KL, VF);
  k_attn<<<dim3(B_SZ * 64), dim3(256), 0, stream>>>(
      QH, KH, KL, VF, x, w_W, b_W, z);
}